// Round 3
// baseline (2101.843 us; speedup 1.0000x reference)
//
#include <hip/hip_runtime.h>

#define Bb 2
#define Ss 1024
#define Dd 1024
#define Ll 512
#define Hh 16
#define HDd 32
#define Ff 2048
#define Ee 8
#define Tt 2048   // B*S
#define EPSf 1e-5f
#define THETAf 10000.0f

typedef unsigned short u16;
typedef unsigned int u32;
typedef short s16x8 __attribute__((ext_vector_type(8)));
typedef float f32x4 __attribute__((ext_vector_type(4)));

__device__ __forceinline__ float bf2f(u16 u) {
    union { u32 i; float f; } v; v.i = ((u32)u) << 16; return v.f;
}
__device__ __forceinline__ u16 f2bf(float f) {
    union { float f; u32 i; } v; v.f = f;
    u32 u = v.i;
    u32 r = (u + 0x7FFFu + ((u >> 16) & 1u)) >> 16;
    return (u16)r;
}

// ---------------------------------------------------------------------------
// rmsnorm from f32 input -> split bf16 hi/lo planes (for split-MFMA GEMM)
__global__ __launch_bounds__(256) void rmsnorm1_k(const float* __restrict__ x,
                                                  const float* __restrict__ g,
                                                  u16* __restrict__ hhi,
                                                  u16* __restrict__ hlo) {
    int row = blockIdx.x, tid = threadIdx.x;
    __shared__ float red[256];
    float xv[4]; float ss = 0.f;
    #pragma unroll
    for (int i = 0; i < 4; i++) {
        int d = tid + i * 256;
        xv[i] = x[(size_t)row * Dd + d];
        ss += xv[i] * xv[i];
    }
    red[tid] = ss; __syncthreads();
    for (int s2 = 128; s2 > 0; s2 >>= 1) {
        if (tid < s2) red[tid] += red[tid + s2];
        __syncthreads();
    }
    float scale = rsqrtf(red[0] / (float)Dd + EPSf);
    #pragma unroll
    for (int i = 0; i < 4; i++) {
        int d = tid + i * 256;
        float h = xv[i] * g[d] * scale;
        u16 hi = f2bf(h);
        hhi[(size_t)row * Dd + d] = hi;
        hlo[(size_t)row * Dd + d] = f2bf(h - bf2f(hi));
    }
}

// rmsnorm2 + fused router: f32 in -> bf16 t2h; pure-f32 logits -> top2 +
// gates + atomic expert bucketing (np top-k fidelity).
__global__ __launch_bounds__(256) void rmsnorm2_router_k(
    const float* __restrict__ x2, const float* __restrict__ g,
    const float* __restrict__ rw, u16* __restrict__ t2h,
    float* __restrict__ gate_w, int* __restrict__ counts,
    int* __restrict__ list_tok, int* __restrict__ list_gid) {
    int row = blockIdx.x, tid = threadIdx.x;
    __shared__ float red[256];
    __shared__ float pw[4][8];
    float xv[4]; float ss = 0.f;
    #pragma unroll
    for (int i = 0; i < 4; i++) {
        int d = tid + i * 256;
        xv[i] = x2[(size_t)row * Dd + d];
        ss += xv[i] * xv[i];
    }
    red[tid] = ss; __syncthreads();
    for (int s2 = 128; s2 > 0; s2 >>= 1) {
        if (tid < s2) red[tid] += red[tid + s2];
        __syncthreads();
    }
    float scale = rsqrtf(red[0] / (float)Dd + EPSf);
    float pl[Ee];
    #pragma unroll
    for (int e = 0; e < Ee; e++) pl[e] = 0.f;
    #pragma unroll
    for (int i = 0; i < 4; i++) {
        int d = tid + i * 256;
        float h = xv[i] * g[d] * scale;
        t2h[(size_t)row * Dd + d] = f2bf(h);
        const float4* rp = (const float4*)(rw + (size_t)d * Ee);
        float4 r0 = rp[0], r1 = rp[1];
        pl[0] += h * r0.x; pl[1] += h * r0.y; pl[2] += h * r0.z; pl[3] += h * r0.w;
        pl[4] += h * r1.x; pl[5] += h * r1.y; pl[6] += h * r1.z; pl[7] += h * r1.w;
    }
    #pragma unroll
    for (int off = 32; off > 0; off >>= 1) {
        #pragma unroll
        for (int e = 0; e < Ee; e++) pl[e] += __shfl_xor(pl[e], off);
    }
    int wv = tid >> 6;
    if ((tid & 63) == 0) {
        #pragma unroll
        for (int e = 0; e < Ee; e++) pw[wv][e] = pl[e];
    }
    __syncthreads();
    if (tid == 0) {
        float p[Ee];
        #pragma unroll
        for (int e = 0; e < Ee; e++) p[e] = pw[0][e] + pw[1][e] + pw[2][e] + pw[3][e];
        int i0 = 0;
        for (int e = 1; e < Ee; e++) if (p[e] > p[i0]) i0 = e;
        int i1 = (i0 == 0) ? 1 : 0;
        for (int e = 0; e < Ee; e++) if (e != i0 && p[e] > p[i1]) i1 = e;
        float e1 = expf(p[i1] - p[i0]);
        float w0 = 1.f / (1.f + e1), w1 = e1 / (1.f + e1);
        gate_w[2 * row] = w0;
        gate_w[2 * row + 1] = w1;
        int p0 = atomicAdd(&counts[i0], 1);
        list_tok[i0 * Tt + p0] = row;
        list_gid[i0 * Tt + p0] = 2 * row;
        int p1 = atomicAdd(&counts[i1], 1);
        list_tok[i1 * Tt + p1] = row;
        list_gid[i1 * Tt + p1] = 2 * row + 1;
    }
}

// ---------------------------------------------------------------------------
// MFMA GEMM, 64x64 tile, 4 waves, K-chunk 32. A = bf16 hi(/lo) planes in ws;
// B = f32 in HBM, converted to bf16 (hi, and lo if BSPLIT) during staging.
// SPLITA+BSPLIT: 3 MFMAs (hi*hi + lo*hi + hi*lo) ~= f32 fidelity.
// GLU: second B matrix, epilogue silu(acc)*acc3 -> bf16.
// GATHER: A rows via arow[], C rows via crow[], count from *cntp.
// EPI: 0 f32 C; 1 split bf16 C; 2 f32 C + f32 residual; 3 GLU bf16 C;
//      4 atomic scatter gate[gid]*v into Cf row gid>>1.
template <int SPLITA, int BSPLIT, int GLU, int GATHER, int EPI>
__global__ __launch_bounds__(256) void gemm_k(
    const u16* __restrict__ Ah, const u16* __restrict__ Al,
    const float* __restrict__ B1, const float* __restrict__ B3,
    int M, int N, int Kd, int lda, int ldb, int ldc,
    const int* __restrict__ arow, const int* __restrict__ crow,
    const int* __restrict__ cntp, const float* __restrict__ gate_f,
    float* __restrict__ Cf, u16* __restrict__ Chi, u16* __restrict__ Clo,
    const float* __restrict__ residf, u16* __restrict__ Cbf) {
    __shared__ u16 As[64][33];
    __shared__ u16 Als[64][33];
    __shared__ u16 Bs[32][65];
    __shared__ u16 Bx[32][65];   // BSPLIT: B-lo ; GLU: B3-hi
    int tid = threadIdx.x;
    int row0 = blockIdx.y * 64, col0 = blockIdx.x * 64;
    int cnt = GATHER ? *cntp : M;
    if (row0 >= cnt) return;
    int lane = tid & 63, wv = tid >> 6;
    int m = lane & 15, qq = lane >> 4;
    f32x4 acc[4]; f32x4 acc3[4];
    #pragma unroll
    for (int i = 0; i < 4; i++) {
        acc[i] = (f32x4){0.f, 0.f, 0.f, 0.f};
        acc3[i] = (f32x4){0.f, 0.f, 0.f, 0.f};
    }
    int ra = tid >> 2, kca = (tid & 3) * 8;
    int rb = tid >> 3, ncb = (tid & 7) * 8;
    int ar = row0 + ra;
    if (GATHER) ar = arow[min(ar, cnt - 1)];
    const u16* pA = Ah + (size_t)ar * lda + kca;
    const u16* pAl = SPLITA ? (Al + (size_t)ar * lda + kca) : (const u16*)nullptr;

    for (int k0 = 0; k0 < Kd; k0 += 32) {
        {
            uint4 av = *(const uint4*)(pA + k0);
            const u16* s = (const u16*)&av;
            #pragma unroll
            for (int j = 0; j < 8; j++) As[ra][kca + j] = s[j];
            if (SPLITA) {
                uint4 av2 = *(const uint4*)(pAl + k0);
                const u16* s2 = (const u16*)&av2;
                #pragma unroll
                for (int j = 0; j < 8; j++) Als[ra][kca + j] = s2[j];
            }
            const float* pB = B1 + (size_t)(k0 + rb) * ldb + col0 + ncb;
            float4 b0 = *(const float4*)pB;
            float4 b1 = *(const float4*)(pB + 4);
            float bb[8] = {b0.x, b0.y, b0.z, b0.w, b1.x, b1.y, b1.z, b1.w};
            #pragma unroll
            for (int j = 0; j < 8; j++) {
                u16 hi = f2bf(bb[j]);
                Bs[rb][ncb + j] = hi;
                if (BSPLIT) Bx[rb][ncb + j] = f2bf(bb[j] - bf2f(hi));
            }
            if (GLU) {
                const float* pB3 = B3 + (size_t)(k0 + rb) * ldb + col0 + ncb;
                float4 c0 = *(const float4*)pB3;
                float4 c1 = *(const float4*)(pB3 + 4);
                float cc[8] = {c0.x, c0.y, c0.z, c0.w, c1.x, c1.y, c1.z, c1.w};
                #pragma unroll
                for (int j = 0; j < 8; j++) Bx[rb][ncb + j] = f2bf(cc[j]);
            }
        }
        __syncthreads();
        s16x8 af, al2;
        #pragma unroll
        for (int j = 0; j < 8; j++) af[j] = (short)As[wv * 16 + m][qq * 8 + j];
        if (SPLITA) {
            #pragma unroll
            for (int j = 0; j < 8; j++) al2[j] = (short)Als[wv * 16 + m][qq * 8 + j];
        }
        #pragma unroll
        for (int ct = 0; ct < 4; ct++) {
            s16x8 bf;
            #pragma unroll
            for (int j = 0; j < 8; j++) bf[j] = (short)Bs[qq * 8 + j][ct * 16 + m];
            acc[ct] = __builtin_amdgcn_mfma_f32_16x16x32_bf16(af, bf, acc[ct], 0, 0, 0);
            if (SPLITA)
                acc[ct] = __builtin_amdgcn_mfma_f32_16x16x32_bf16(al2, bf, acc[ct], 0, 0, 0);
            if (BSPLIT) {
                s16x8 bl;
                #pragma unroll
                for (int j = 0; j < 8; j++) bl[j] = (short)Bx[qq * 8 + j][ct * 16 + m];
                acc[ct] = __builtin_amdgcn_mfma_f32_16x16x32_bf16(af, bl, acc[ct], 0, 0, 0);
            }
            if (GLU) {
                s16x8 b3;
                #pragma unroll
                for (int j = 0; j < 8; j++) b3[j] = (short)Bx[qq * 8 + j][ct * 16 + m];
                acc3[ct] = __builtin_amdgcn_mfma_f32_16x16x32_bf16(af, b3, acc3[ct], 0, 0, 0);
            }
        }
        __syncthreads();
    }
    // epilogue — C/D layout: col = lane&15, row = (lane>>4)*4 + reg (m89/m91)
    #pragma unroll
    for (int ct = 0; ct < 4; ct++) {
        #pragma unroll
        for (int rg = 0; rg < 4; rg++) {
            int gr = row0 + wv * 16 + qq * 4 + rg;
            int gc = col0 + ct * 16 + m;
            if (GATHER && gr >= cnt) continue;
            float v = acc[ct][rg];
            if (EPI == 4) {
                int gid = crow[gr];
                int tok = gid >> 1;
                atomicAdd(&Cf[(size_t)tok * ldc + gc], gate_f[gid] * v);
                continue;
            }
            size_t cix;
            if (GATHER) cix = (size_t)crow[gr] * ldc + gc;
            else cix = (size_t)gr * ldc + gc;
            if (EPI == 0) {
                Cf[cix] = v;
            } else if (EPI == 1) {
                u16 hi = f2bf(v);
                Chi[cix] = hi;
                Clo[cix] = f2bf(v - bf2f(hi));
            } else if (EPI == 2) {
                Cf[cix] = v + residf[cix];
            } else if (EPI == 3) {
                float sg = v / (1.f + expf(-v));
                Cbf[cix] = f2bf(sg * acc3[ct][rg]);
            }
        }
    }
}

// ---------------------------------------------------------------------------
// RoPE in place on f32 q,k. One block per token, thread = (head, pair).
__global__ __launch_bounds__(256) void rope_k(float* __restrict__ q, float* __restrict__ k) {
    int t = blockIdx.x, tid = threadIdx.x;
    int h = tid >> 4, i = tid & 15;
    int pos = t & (Ss - 1);
    float inv = powf(THETAf, -((float)(2 * i)) / (float)HDd);
    float ang = (float)pos * inv;
    float c = cosf(ang), sn = sinf(ang);
    size_t base = (size_t)t * Ll + h * HDd + 2 * i;
    float q1 = q[base], q2 = q[base + 1];
    q[base] = q1 * c - q2 * sn;
    q[base + 1] = q1 * sn + q2 * c;
    float k1 = k[base], k2 = k[base + 1];
    k[base] = k1 * c - k2 * sn;
    k[base + 1] = k1 * sn + k2 * c;
}

// ---------------------------------------------------------------------------
// Causal attention, f32, online softmax. One wave per (b,h,q) row.
__global__ __launch_bounds__(64) void attn_k(const float* __restrict__ qf,
                                             const float* __restrict__ kf,
                                             const float* __restrict__ vf,
                                             u16* __restrict__ ohi, u16* __restrict__ olo) {
    const float SCALE = 0.1767766952966369f; // 1/sqrt(32)
    int blk = blockIdx.x;
    int qi = blk & (Ss - 1);
    int bh = blk >> 10;
    int h = bh & (Hh - 1);
    int b = bh >> 4;
    int t = b * Ss + qi;
    int lane = threadIdx.x;
    __shared__ float qs[32];
    __shared__ float ks[64][33];
    __shared__ float vs[64][33];
    __shared__ float ps[64];
    if (lane < 32) qs[lane] = qf[(size_t)t * Ll + h * HDd + lane];
    __syncthreads();
    float mrun = -1e30f, lrun = 0.f, oacc = 0.f;
    int d = lane & 31, half = lane >> 5;
    int ntiles = (qi >> 6) + 1;
    for (int kt = 0; kt < ntiles; kt++) {
        int kbase = kt * 64;
        #pragma unroll 4
        for (int i = 0; i < 32; i++) {
            int e = i * 64 + lane;
            int kk = e >> 5, dd = e & 31;
            int krow = b * Ss + min(kbase + kk, Ss - 1); // clamp inside batch; masked anyway
            ks[kk][dd] = kf[(size_t)krow * Ll + h * HDd + dd];
            vs[kk][dd] = vf[(size_t)krow * Ll + h * HDd + dd];
        }
        __syncthreads();
        int kidx = kbase + lane;
        float s = -1e30f;
        if (kidx <= qi) {
            float a = 0.f;
            #pragma unroll
            for (int dd = 0; dd < 32; dd++) a += qs[dd] * ks[lane][dd];
            s = a * SCALE;
        }
        float tm = s;
        #pragma unroll
        for (int off = 32; off > 0; off >>= 1) tm = fmaxf(tm, __shfl_xor(tm, off));
        float mnew = fmaxf(mrun, tm);
        float pv = (kidx <= qi) ? expf(s - mnew) : 0.f;
        float tsum = pv;
        #pragma unroll
        for (int off = 32; off > 0; off >>= 1) tsum += __shfl_xor(tsum, off);
        float alpha = expf(mrun - mnew);
        lrun = lrun * alpha + tsum;
        oacc *= alpha;
        ps[lane] = pv;
        __syncthreads();
        #pragma unroll 8
        for (int j2 = 0; j2 < 32; j2++) {
            int j = half * 32 + j2;
            oacc += ps[j] * vs[j][d];
        }
        mrun = mnew;
        __syncthreads();
    }
    oacc += __shfl_xor(oacc, 32);
    if (lane < 32) {
        float o = oacc / lrun;
        u16 hi = f2bf(o);
        ohi[(size_t)t * Ll + h * HDd + d] = hi;
        olo[(size_t)t * Ll + h * HDd + d] = f2bf(o - bf2f(hi));
    }
}

// ---------------------------------------------------------------------------
// out += x2   (out already holds the gated MoE sum via atomics)
__global__ __launch_bounds__(256) void final_k(const float* __restrict__ x2,
                                               float* __restrict__ out) {
    int t = blockIdx.x, tid = threadIdx.x;
    #pragma unroll
    for (int i = 0; i < 4; i++) {
        int d = tid + i * 256;
        size_t ix = (size_t)t * Dd + d;
        out[ix] = out[ix] + x2[ix];
    }
}

// ---------------------------------------------------------------------------
extern "C" void kernel_launch(void* const* d_in, const int* in_sizes, int n_in,
                              void* d_out, int out_size, void* d_ws, size_t ws_size,
                              hipStream_t stream) {
    const float* x       = (const float*)d_in[0];
    const float* g1      = (const float*)d_in[1];
    const float* g2      = (const float*)d_in[2];
    const float* w_down  = (const float*)d_in[3];
    const float* wq      = (const float*)d_in[4];
    const float* wk      = (const float*)d_in[5];
    const float* wv      = (const float*)d_in[6];
    const float* w_up    = (const float*)d_in[7];
    const float* rw      = (const float*)d_in[8];
    const float* w1      = (const float*)d_in[9];
    const float* w3      = (const float*)d_in[10];
    const float* w2      = (const float*)d_in[11];
    float* out = (float*)d_out;

    // --- workspace overlay (total ~28.2 MB) ---
    char* S = (char*)d_ws;                         // 16 MB time-shared scratch
    // phase 1: rmsnorm1 + c-GEMM
    u16*   h_hi = (u16*)(S + (size_t)0);           // 4 MB [0,4M)
    u16*   h_lo = (u16*)(S + ((size_t)4 << 20));   // 4 MB [4M,8M)
    u16*   c_hi = (u16*)(S + ((size_t)8 << 20));   // 2 MB [8M,10M)
    u16*   c_lo = (u16*)(S + ((size_t)10 << 20));  // 2 MB [10M,12M)
    // phase 2/3: qkv + attention (h dead after c; c dead after v)
    float* qf   = (float*)(S + (size_t)0);         // 4 MB [0,4M)
    float* kf   = (float*)(S + ((size_t)4 << 20)); // 4 MB [4M,8M)
    float* vf   = (float*)(S + ((size_t)12 << 20));// 4 MB [12M,16M)
    u16*   o_hi = (u16*)(S + ((size_t)8 << 20));   // 2 MB [8M,10M)
    u16*   o_lo = (u16*)(S + ((size_t)10 << 20));  // 2 MB [10M,12M)
    // phase 4: MoE hidden (everything in S dead)
    u16*   hid  = (u16*)(S + (size_t)0);           // 16 MB [0,16M)
    char* p = (char*)d_ws + ((size_t)16 << 20);
    u16*   t2h    = (u16*)p;   p += (size_t)Tt * Dd * 2;      // 4 MB
    float* x2f    = (float*)p; p += (size_t)Tt * Dd * 4;      // 8 MB
    float* gate_w = (float*)p; p += (size_t)Tt * 2 * 4;       // 16 KB
    int*   counts = (int*)p;   p += 256;
    int*   l_tok  = (int*)p;   p += (size_t)Ee * Tt * 4;      // 64 KB
    int*   l_gid  = (int*)p;   p += (size_t)Ee * Tt * 4;      // 64 KB

    hipMemsetAsync(counts, 0, 256, stream);
    hipMemsetAsync(out, 0, (size_t)Tt * Dd * 4, stream);  // MoE accumulator

    rmsnorm1_k<<<Tt, 256, 0, stream>>>(x, g1, h_hi, h_lo);

    // c = h @ w_down  (split x split, split-out epilogue)
    gemm_k<1, 1, 0, 0, 1><<<dim3(Ll / 64, Tt / 64), 256, 0, stream>>>(
        h_hi, h_lo, w_down, nullptr, Tt, Ll, Dd, Dd, Ll, Ll,
        nullptr, nullptr, nullptr, nullptr, nullptr, c_hi, c_lo, nullptr, nullptr);

    // q,k,v = c @ wq/wk/wv  (split x split, f32 out)
    gemm_k<1, 1, 0, 0, 0><<<dim3(Ll / 64, Tt / 64), 256, 0, stream>>>(
        c_hi, c_lo, wq, nullptr, Tt, Ll, Ll, Ll, Ll, Ll,
        nullptr, nullptr, nullptr, nullptr, qf, nullptr, nullptr, nullptr, nullptr);
    gemm_k<1, 1, 0, 0, 0><<<dim3(Ll / 64, Tt / 64), 256, 0, stream>>>(
        c_hi, c_lo, wk, nullptr, Tt, Ll, Ll, Ll, Ll, Ll,
        nullptr, nullptr, nullptr, nullptr, kf, nullptr, nullptr, nullptr, nullptr);
    gemm_k<1, 1, 0, 0, 0><<<dim3(Ll / 64, Tt / 64), 256, 0, stream>>>(
        c_hi, c_lo, wv, nullptr, Tt, Ll, Ll, Ll, Ll, Ll,
        nullptr, nullptr, nullptr, nullptr, vf, nullptr, nullptr, nullptr, nullptr);

    rope_k<<<Tt, 256, 0, stream>>>(qf, kf);

    attn_k<<<Bb * Hh * Ss, 64, 0, stream>>>(qf, kf, vf, o_hi, o_lo);

    // x2 = x + o @ w_up  (split x split, f32 residual epilogue)
    gemm_k<1, 1, 0, 0, 2><<<dim3(Dd / 64, Tt / 64), 256, 0, stream>>>(
        o_hi, o_lo, w_up, nullptr, Tt, Dd, Ll, Ll, Dd, Dd,
        nullptr, nullptr, nullptr, nullptr, x2f, nullptr, nullptr, x, nullptr);

    rmsnorm2_router_k<<<Tt, 256, 0, stream>>>(x2f, g2, rw, t2h, gate_w,
                                              counts, l_tok, l_gid);

    // MoE: grouped per-expert GLU GEMM then down-proj GEMM w/ atomic combine
    for (int e = 0; e < Ee; e++) {
        gemm_k<0, 0, 1, 1, 3><<<dim3(Ff / 64, Tt / 64), 256, 0, stream>>>(
            t2h, nullptr, w1 + (size_t)e * Dd * Ff, w3 + (size_t)e * Dd * Ff,
            Tt, Ff, Dd, Dd, Ff, Ff,
            l_tok + e * Tt, l_gid + e * Tt, counts + e, nullptr,
            nullptr, nullptr, nullptr, nullptr, hid);
    }
    for (int e = 0; e < Ee; e++) {
        gemm_k<0, 0, 0, 1, 4><<<dim3(Dd / 64, Tt / 64), 256, 0, stream>>>(
            hid, nullptr, w2 + (size_t)e * Ff * Dd, nullptr,
            Tt, Dd, Ff, Ff, Dd, Dd,
            l_gid + e * Tt, l_gid + e * Tt, counts + e, gate_w,
            out, nullptr, nullptr, nullptr, nullptr);
    }

    final_k<<<Tt, 256, 0, stream>>>(x2f, out);
}

// Round 4
// 645.384 us; speedup vs baseline: 3.2567x; 3.2567x over previous
//
#include <hip/hip_runtime.h>

#define Bb 2
#define Ss 1024
#define Dd 1024
#define Ll 512
#define Hh 16
#define HDd 32
#define Ff 2048
#define Ee 8
#define Tt 2048   // B*S
#define EPSf 1e-5f
#define THETAf 10000.0f

typedef unsigned short u16;
typedef unsigned int u32;
typedef short s16x8 __attribute__((ext_vector_type(8)));
typedef float f32x4 __attribute__((ext_vector_type(4)));

__device__ __forceinline__ float bf2f(u16 u) {
    union { u32 i; float f; } v; v.i = ((u32)u) << 16; return v.f;
}
__device__ __forceinline__ u16 f2bf(float f) {
    union { float f; u32 i; } v; v.f = f;
    u32 u = v.i;
    u32 r = (u + 0x7FFFu + ((u >> 16) & 1u)) >> 16;
    return (u16)r;
}

// ---------------------------------------------------------------------------
// rmsnorm from f32 input -> split bf16 hi/lo planes (for split-MFMA GEMM)
__global__ __launch_bounds__(256) void rmsnorm1_k(const float* __restrict__ x,
                                                  const float* __restrict__ g,
                                                  u16* __restrict__ hhi,
                                                  u16* __restrict__ hlo) {
    int row = blockIdx.x, tid = threadIdx.x;
    __shared__ float red[256];
    float xv[4]; float ss = 0.f;
    #pragma unroll
    for (int i = 0; i < 4; i++) {
        int d = tid + i * 256;
        xv[i] = x[(size_t)row * Dd + d];
        ss += xv[i] * xv[i];
    }
    red[tid] = ss; __syncthreads();
    for (int s2 = 128; s2 > 0; s2 >>= 1) {
        if (tid < s2) red[tid] += red[tid + s2];
        __syncthreads();
    }
    float scale = rsqrtf(red[0] / (float)Dd + EPSf);
    #pragma unroll
    for (int i = 0; i < 4; i++) {
        int d = tid + i * 256;
        float h = xv[i] * g[d] * scale;
        u16 hi = f2bf(h);
        hhi[(size_t)row * Dd + d] = hi;
        hlo[(size_t)row * Dd + d] = f2bf(h - bf2f(hi));
    }
}

// rmsnorm2 + fused router (pure-f32 logits; np top-k fidelity)
__global__ __launch_bounds__(256) void rmsnorm2_router_k(
    const float* __restrict__ x2, const float* __restrict__ g,
    const float* __restrict__ rw, u16* __restrict__ t2h,
    float* __restrict__ gate_w, int* __restrict__ counts,
    int* __restrict__ list_tok, int* __restrict__ list_gid) {
    int row = blockIdx.x, tid = threadIdx.x;
    __shared__ float red[256];
    __shared__ float pw[4][8];
    float xv[4]; float ss = 0.f;
    #pragma unroll
    for (int i = 0; i < 4; i++) {
        int d = tid + i * 256;
        xv[i] = x2[(size_t)row * Dd + d];
        ss += xv[i] * xv[i];
    }
    red[tid] = ss; __syncthreads();
    for (int s2 = 128; s2 > 0; s2 >>= 1) {
        if (tid < s2) red[tid] += red[tid + s2];
        __syncthreads();
    }
    float scale = rsqrtf(red[0] / (float)Dd + EPSf);
    float pl[Ee];
    #pragma unroll
    for (int e = 0; e < Ee; e++) pl[e] = 0.f;
    #pragma unroll
    for (int i = 0; i < 4; i++) {
        int d = tid + i * 256;
        float h = xv[i] * g[d] * scale;
        t2h[(size_t)row * Dd + d] = f2bf(h);
        const float4* rp = (const float4*)(rw + (size_t)d * Ee);
        float4 r0 = rp[0], r1 = rp[1];
        pl[0] += h * r0.x; pl[1] += h * r0.y; pl[2] += h * r0.z; pl[3] += h * r0.w;
        pl[4] += h * r1.x; pl[5] += h * r1.y; pl[6] += h * r1.z; pl[7] += h * r1.w;
    }
    #pragma unroll
    for (int off = 32; off > 0; off >>= 1) {
        #pragma unroll
        for (int e = 0; e < Ee; e++) pl[e] += __shfl_xor(pl[e], off);
    }
    int wv = tid >> 6;
    if ((tid & 63) == 0) {
        #pragma unroll
        for (int e = 0; e < Ee; e++) pw[wv][e] = pl[e];
    }
    __syncthreads();
    if (tid == 0) {
        float p[Ee];
        #pragma unroll
        for (int e = 0; e < Ee; e++) p[e] = pw[0][e] + pw[1][e] + pw[2][e] + pw[3][e];
        int i0 = 0;
        for (int e = 1; e < Ee; e++) if (p[e] > p[i0]) i0 = e;
        int i1 = (i0 == 0) ? 1 : 0;
        for (int e = 0; e < Ee; e++) if (e != i0 && p[e] > p[i1]) i1 = e;
        float e1 = expf(p[i1] - p[i0]);
        float w0 = 1.f / (1.f + e1), w1 = e1 / (1.f + e1);
        gate_w[2 * row] = w0;
        gate_w[2 * row + 1] = w1;
        int p0 = atomicAdd(&counts[i0], 1);
        list_tok[i0 * Tt + p0] = row;
        list_gid[i0 * Tt + p0] = 2 * row;
        int p1 = atomicAdd(&counts[i1], 1);
        list_tok[i1 * Tt + p1] = row;
        list_gid[i1 * Tt + p1] = 2 * row + 1;
    }
}

// ---------------------------------------------------------------------------
// MFMA GEMM, 64x64 tile, 4 waves, K-chunk 32.
// LDS: A natural [m][k] stride 40 (b128 r/w); B transposed [n][k] stride 40
// with XOR chunk swizzle c^=((n>>3)&3) -> conflict-free writes, b128 reads.
// SPLITA: A hi+lo planes. BSPLIT: B f32 -> hi+lo (3-MFMA f32 fidelity).
// GLU: second B, epilogue silu(acc)*acc3. GATHER: A/C rows via lists.
// EPI: 0 f32 C; 1 split bf16 C; 2 f32 C + f32 resid; 3 GLU bf16 C;
//      4 atomic gate[gid]*v into Cf row gid>>1.
// ZM: 0 none; 1 qkv (B from {B1,B3,B2} by z, C += z*czs); 2 moe (B += z*bzs,
//     lists += z*Tt, cnt = cntp[z]).
template <int SPLITA, int BSPLIT, int GLU, int GATHER, int EPI, int ZM>
__global__ __launch_bounds__(256) void gemm_k(
    const u16* __restrict__ Ah, const u16* __restrict__ Al,
    const float* __restrict__ B1, const float* __restrict__ B3,
    const float* __restrict__ B2,
    int M, int N, int Kd, int lda, int ldb, int ldc, long bzs, long czs,
    const int* __restrict__ arow, const int* __restrict__ crow,
    const int* __restrict__ cntp, const float* __restrict__ gate_f,
    float* __restrict__ Cf, u16* __restrict__ Chi, u16* __restrict__ Clo,
    const float* __restrict__ residf, u16* __restrict__ Cbf) {
    __shared__ __align__(16) u16 As[64 * 40];
    __shared__ __align__(16) u16 Als[64 * 40];
    __shared__ __align__(16) u16 Bs[64 * 40];
    __shared__ __align__(16) u16 Bx[64 * 40];
    int tid = threadIdx.x;
    int row0 = blockIdx.y * 64, col0 = blockIdx.x * 64;
    int z = ZM ? blockIdx.z : 0;
    const float* Bp = B1;
    const float* B3p = B3;
    if (ZM == 1) Bp = (z == 0) ? B1 : ((z == 1) ? B3 : B2);
    if (ZM == 2) {
        Bp = B1 + (size_t)z * bzs;
        if (GLU) B3p = B3 + (size_t)z * bzs;
    }
    const int* arp = arow;
    const int* crp = crow;
    if (ZM == 2 && GATHER) { arp = arow + z * Tt; crp = crow + z * Tt; }
    int cnt = GATHER ? cntp[ZM == 2 ? z : 0] : M;
    if (row0 >= cnt) return;
    float* Cfp = (ZM == 1) ? (Cf + (size_t)z * czs) : Cf;

    int lane = tid & 63, wv = tid >> 6;
    int m = lane & 15, qq = lane >> 4;
    f32x4 acc[4]; f32x4 acc3[4];
    #pragma unroll
    for (int i = 0; i < 4; i++) {
        acc[i] = (f32x4){0.f, 0.f, 0.f, 0.f};
        acc3[i] = (f32x4){0.f, 0.f, 0.f, 0.f};
    }
    int ra = tid >> 2, kca = (tid & 3) * 8;     // A staging: row, k-offset
    int rb = tid >> 3, ncb = (tid & 7) * 8;     // B staging: k row, n-offset
    int ar = row0 + ra;
    if (GATHER) ar = arp[min(ar, cnt - 1)];
    const u16* pA = Ah + (size_t)ar * lda + kca;
    const u16* pAl = SPLITA ? (Al + (size_t)ar * lda + kca) : (const u16*)nullptr;
    int cb = rb >> 3;                            // B chunk index (k>>3)

    for (int k0 = 0; k0 < Kd; k0 += 32) {
        {
            uint4 av = *(const uint4*)(pA + k0);
            *(uint4*)(As + ra * 40 + kca) = av;
            if (SPLITA) {
                uint4 av2 = *(const uint4*)(pAl + k0);
                *(uint4*)(Als + ra * 40 + kca) = av2;
            }
            const float* pB = Bp + (size_t)(k0 + rb) * ldb + col0 + ncb;
            float4 b0 = *(const float4*)pB;
            float4 b1 = *(const float4*)(pB + 4);
            float bb[8] = {b0.x, b0.y, b0.z, b0.w, b1.x, b1.y, b1.z, b1.w};
            #pragma unroll
            for (int j = 0; j < 8; j++) {
                int n = ncb + j;
                int c2 = cb ^ ((n >> 3) & 3);
                int koff = (c2 << 3) | (rb & 7);
                u16 hi = f2bf(bb[j]);
                Bs[n * 40 + koff] = hi;
                if (BSPLIT) Bx[n * 40 + koff] = f2bf(bb[j] - bf2f(hi));
            }
            if (GLU) {
                const float* pB3 = B3p + (size_t)(k0 + rb) * ldb + col0 + ncb;
                float4 c0 = *(const float4*)pB3;
                float4 c1 = *(const float4*)(pB3 + 4);
                float cc[8] = {c0.x, c0.y, c0.z, c0.w, c1.x, c1.y, c1.z, c1.w};
                #pragma unroll
                for (int j = 0; j < 8; j++) {
                    int n = ncb + j;
                    int c2 = cb ^ ((n >> 3) & 3);
                    int koff = (c2 << 3) | (rb & 7);
                    Bx[n * 40 + koff] = f2bf(cc[j]);
                }
            }
        }
        __syncthreads();
        s16x8 af = *(const s16x8*)(As + (wv * 16 + m) * 40 + qq * 8);
        s16x8 al2;
        if (SPLITA) al2 = *(const s16x8*)(Als + (wv * 16 + m) * 40 + qq * 8);
        #pragma unroll
        for (int ct = 0; ct < 4; ct++) {
            int n = ct * 16 + m;
            int c2 = qq ^ ((n >> 3) & 3);
            s16x8 bf = *(const s16x8*)(Bs + n * 40 + c2 * 8);
            acc[ct] = __builtin_amdgcn_mfma_f32_16x16x32_bf16(af, bf, acc[ct], 0, 0, 0);
            if (SPLITA)
                acc[ct] = __builtin_amdgcn_mfma_f32_16x16x32_bf16(al2, bf, acc[ct], 0, 0, 0);
            if (BSPLIT) {
                s16x8 bl = *(const s16x8*)(Bx + n * 40 + c2 * 8);
                acc[ct] = __builtin_amdgcn_mfma_f32_16x16x32_bf16(af, bl, acc[ct], 0, 0, 0);
            }
            if (GLU) {
                s16x8 b3 = *(const s16x8*)(Bx + n * 40 + c2 * 8);
                acc3[ct] = __builtin_amdgcn_mfma_f32_16x16x32_bf16(af, b3, acc3[ct], 0, 0, 0);
            }
        }
        __syncthreads();
    }
    // epilogue — C/D layout: col = lane&15, row = (lane>>4)*4 + reg (m89/m91)
    #pragma unroll
    for (int ct = 0; ct < 4; ct++) {
        #pragma unroll
        for (int rg = 0; rg < 4; rg++) {
            int gr = row0 + wv * 16 + qq * 4 + rg;
            int gc = col0 + ct * 16 + m;
            if (GATHER && gr >= cnt) continue;
            float v = acc[ct][rg];
            if (EPI == 4) {
                int gid = crp[gr];
                int tok = gid >> 1;
                atomicAdd(&Cfp[(size_t)tok * ldc + gc], gate_f[gid] * v);
                continue;
            }
            size_t cix;
            if (GATHER) cix = (size_t)crp[gr] * ldc + gc;
            else cix = (size_t)gr * ldc + gc;
            if (EPI == 0) {
                Cfp[cix] = v;
            } else if (EPI == 1) {
                u16 hi = f2bf(v);
                Chi[cix] = hi;
                Clo[cix] = f2bf(v - bf2f(hi));
            } else if (EPI == 2) {
                Cfp[cix] = v + residf[cix];
            } else if (EPI == 3) {
                float sg = v / (1.f + expf(-v));
                Cbf[cix] = f2bf(sg * acc3[ct][rg]);
            }
        }
    }
}

// ---------------------------------------------------------------------------
// RoPE in place on f32 q,k.
__global__ __launch_bounds__(256) void rope_k(float* __restrict__ q, float* __restrict__ k) {
    int t = blockIdx.x, tid = threadIdx.x;
    int h = tid >> 4, i = tid & 15;
    int pos = t & (Ss - 1);
    float inv = powf(THETAf, -((float)(2 * i)) / (float)HDd);
    float ang = (float)pos * inv;
    float c = cosf(ang), sn = sinf(ang);
    size_t base = (size_t)t * Ll + h * HDd + 2 * i;
    float q1 = q[base], q2 = q[base + 1];
    q[base] = q1 * c - q2 * sn;
    q[base + 1] = q1 * sn + q2 * c;
    float k1 = k[base], k2 = k[base + 1];
    k[base] = k1 * c - k2 * sn;
    k[base + 1] = k1 * sn + k2 * c;
}

// ---------------------------------------------------------------------------
// MFMA flash attention. Block = 64-row Q-tile (4 waves x 16-row strip),
// K/V tiles of 64 staged per block. Split-bf16 (hi+lo, 3 MFMAs) on both
// QK^T and P·V for f32 fidelity (router safety). Online softmax per q-row.
// Grid: (Ss/64, Bb*Hh).
__global__ __launch_bounds__(256) void attn_k(const float* __restrict__ qf,
                                              const float* __restrict__ kf,
                                              const float* __restrict__ vf,
                                              u16* __restrict__ ohi, u16* __restrict__ olo) {
    const float SCALE = 0.1767766952966369f; // 1/sqrt(32)
    int qt = blockIdx.x;
    int bh = blockIdx.y;
    int h = bh & (Hh - 1), b = bh >> 4;
    int tid = threadIdx.x;
    int wv = tid >> 6, lane = tid & 63;
    int m = lane & 15, quad = lane >> 4;

    __shared__ __align__(16) u16 Ksh[64 * 40];       // K natural [key][d]
    __shared__ __align__(16) u16 Ksl[64 * 40];
    __shared__ __align__(16) u16 Vsh[32 * 72];       // V transposed [d][key], swizzled
    __shared__ __align__(16) u16 Vsl[32 * 72];
    __shared__ __align__(16) u16 Ph[4][16 * 72];     // P per wave [qrow][key]
    __shared__ __align__(16) u16 Pl[4][16 * 72];

    // Q A-fragments from global (rows = qt*64 + wv*16 + m, k = quad*8+j)
    int qrow = qt * 64 + wv * 16 + m;
    const float* qp = qf + (size_t)(b * Ss + qrow) * Ll + h * HDd + quad * 8;
    float4 q0 = *(const float4*)qp;
    float4 q1 = *(const float4*)(qp + 4);
    float qvv[8] = {q0.x, q0.y, q0.z, q0.w, q1.x, q1.y, q1.z, q1.w};
    s16x8 qh, ql;
    #pragma unroll
    for (int j = 0; j < 8; j++) {
        u16 hi = f2bf(qvv[j]);
        qh[j] = (short)hi;
        ql[j] = (short)f2bf(qvv[j] - bf2f(hi));
    }

    float mrun[4], lrun[4];
    f32x4 o0 = (f32x4){0.f, 0.f, 0.f, 0.f};
    f32x4 o1 = (f32x4){0.f, 0.f, 0.f, 0.f};
    #pragma unroll
    for (int rg = 0; rg < 4; rg++) { mrun[rg] = -1e30f; lrun[rg] = 0.f; }

    int skey = tid >> 2, sd0 = (tid & 3) * 8;   // staging assignment
    for (int kt = 0; kt <= qt; kt++) {
        int kbase = kt * 64;
        {   // stage K (b128) and V (transposed + swizzled scalar)
            const float* kp = kf + (size_t)(b * Ss + kbase + skey) * Ll + h * HDd + sd0;
            float4 a0 = *(const float4*)kp;
            float4 a1 = *(const float4*)(kp + 4);
            float kvv[8] = {a0.x, a0.y, a0.z, a0.w, a1.x, a1.y, a1.z, a1.w};
            s16x8 khv, klv;
            #pragma unroll
            for (int j = 0; j < 8; j++) {
                u16 hi = f2bf(kvv[j]);
                khv[j] = (short)hi;
                klv[j] = (short)f2bf(kvv[j] - bf2f(hi));
            }
            *(s16x8*)(Ksh + skey * 40 + sd0) = khv;
            *(s16x8*)(Ksl + skey * 40 + sd0) = klv;
            const float* vp = vf + (size_t)(b * Ss + kbase + skey) * Ll + h * HDd + sd0;
            float4 c0 = *(const float4*)vp;
            float4 c1 = *(const float4*)(vp + 4);
            float vvv[8] = {c0.x, c0.y, c0.z, c0.w, c1.x, c1.y, c1.z, c1.w};
            #pragma unroll
            for (int j = 0; j < 8; j++) {
                int d = sd0 + j;
                int c2 = (skey >> 3) ^ ((d >> 3) & 7);
                int koff = (c2 << 3) | (skey & 7);
                u16 hi = f2bf(vvv[j]);
                Vsh[d * 72 + koff] = hi;
                Vsl[d * 72 + koff] = f2bf(vvv[j] - bf2f(hi));
            }
        }
        __syncthreads();
        // scores: S = Q K^T (split, 3 MFMAs per 16x16)
        f32x4 sc[4];
        #pragma unroll
        for (int ct = 0; ct < 4; ct++) {
            int n = ct * 16 + m;
            s16x8 kh = *(const s16x8*)(Ksh + n * 40 + quad * 8);
            s16x8 kl = *(const s16x8*)(Ksl + n * 40 + quad * 8);
            f32x4 a = (f32x4){0.f, 0.f, 0.f, 0.f};
            a = __builtin_amdgcn_mfma_f32_16x16x32_bf16(qh, kh, a, 0, 0, 0);
            a = __builtin_amdgcn_mfma_f32_16x16x32_bf16(ql, kh, a, 0, 0, 0);
            a = __builtin_amdgcn_mfma_f32_16x16x32_bf16(qh, kl, a, 0, 0, 0);
            sc[ct] = a;
        }
        // mask + online softmax per row (row = quad*4+rg; 16 lanes share row)
        #pragma unroll
        for (int rg = 0; rg < 4; rg++) {
            int qr = qt * 64 + wv * 16 + quad * 4 + rg;
            float s4[4];
            #pragma unroll
            for (int ct = 0; ct < 4; ct++) {
                float sv = sc[ct][rg] * SCALE;
                if (kbase + ct * 16 + m > qr) sv = -1e30f;
                s4[ct] = sv;
            }
            float tm = fmaxf(fmaxf(s4[0], s4[1]), fmaxf(s4[2], s4[3]));
            #pragma unroll
            for (int off = 8; off > 0; off >>= 1) tm = fmaxf(tm, __shfl_xor(tm, off));
            float mnew = fmaxf(mrun[rg], tm);
            float psum = 0.f;
            float p4[4];
            #pragma unroll
            for (int ct = 0; ct < 4; ct++) {
                p4[ct] = expf(s4[ct] - mnew);
                psum += p4[ct];
            }
            #pragma unroll
            for (int off = 8; off > 0; off >>= 1) psum += __shfl_xor(psum, off);
            float alpha = expf(mrun[rg] - mnew);
            mrun[rg] = mnew;
            lrun[rg] = lrun[rg] * alpha + psum;
            o0[rg] *= alpha;
            o1[rg] *= alpha;
            int prow = quad * 4 + rg;
            #pragma unroll
            for (int ct = 0; ct < 4; ct++) {
                u16 hi = f2bf(p4[ct]);
                Ph[wv][prow * 72 + ct * 16 + m] = hi;
                Pl[wv][prow * 72 + ct * 16 + m] = f2bf(p4[ct] - bf2f(hi));
            }
        }
        // PV: O += P V (split); P A-frags from own-wave LDS region
        #pragma unroll
        for (int kc = 0; kc < 2; kc++) {
            s16x8 pah = *(const s16x8*)(Ph[wv] + m * 72 + kc * 32 + quad * 8);
            s16x8 pal = *(const s16x8*)(Pl[wv] + m * 72 + kc * 32 + quad * 8);
            #pragma unroll
            for (int ct = 0; ct < 2; ct++) {
                int d = ct * 16 + m;
                int c2 = (kc * 4 + quad) ^ ((d >> 3) & 7);
                s16x8 vh = *(const s16x8*)(Vsh + d * 72 + c2 * 8);
                s16x8 vl2 = *(const s16x8*)(Vsl + d * 72 + c2 * 8);
                if (ct == 0) {
                    o0 = __builtin_amdgcn_mfma_f32_16x16x32_bf16(pah, vh, o0, 0, 0, 0);
                    o0 = __builtin_amdgcn_mfma_f32_16x16x32_bf16(pal, vh, o0, 0, 0, 0);
                    o0 = __builtin_amdgcn_mfma_f32_16x16x32_bf16(pah, vl2, o0, 0, 0, 0);
                } else {
                    o1 = __builtin_amdgcn_mfma_f32_16x16x32_bf16(pah, vh, o1, 0, 0, 0);
                    o1 = __builtin_amdgcn_mfma_f32_16x16x32_bf16(pal, vh, o1, 0, 0, 0);
                    o1 = __builtin_amdgcn_mfma_f32_16x16x32_bf16(pah, vl2, o1, 0, 0, 0);
                }
            }
        }
        __syncthreads();
    }
    // epilogue: divide by l, write split o planes
    #pragma unroll
    for (int rg = 0; rg < 4; rg++) {
        float inv = 1.f / lrun[rg];
        int tok = b * Ss + qt * 64 + wv * 16 + quad * 4 + rg;
        #pragma unroll
        for (int ct = 0; ct < 2; ct++) {
            float ov = (ct ? o1[rg] : o0[rg]) * inv;
            int d = ct * 16 + m;
            u16 hi = f2bf(ov);
            ohi[(size_t)tok * Ll + h * HDd + d] = hi;
            olo[(size_t)tok * Ll + h * HDd + d] = f2bf(ov - bf2f(hi));
        }
    }
}

// ---------------------------------------------------------------------------
// out += x2   (out already holds the gated MoE sum via atomics)
__global__ __launch_bounds__(256) void final_k(const float* __restrict__ x2,
                                               float* __restrict__ out) {
    int t = blockIdx.x, tid = threadIdx.x;
    #pragma unroll
    for (int i = 0; i < 4; i++) {
        int d = tid + i * 256;
        size_t ix = (size_t)t * Dd + d;
        out[ix] = out[ix] + x2[ix];
    }
}

// ---------------------------------------------------------------------------
extern "C" void kernel_launch(void* const* d_in, const int* in_sizes, int n_in,
                              void* d_out, int out_size, void* d_ws, size_t ws_size,
                              hipStream_t stream) {
    const float* x       = (const float*)d_in[0];
    const float* g1      = (const float*)d_in[1];
    const float* g2      = (const float*)d_in[2];
    const float* w_down  = (const float*)d_in[3];
    const float* wq      = (const float*)d_in[4];
    const float* wk      = (const float*)d_in[5];
    const float* wv      = (const float*)d_in[6];
    const float* w_up    = (const float*)d_in[7];
    const float* rw      = (const float*)d_in[8];
    const float* w1      = (const float*)d_in[9];
    const float* w3      = (const float*)d_in[10];
    const float* w2      = (const float*)d_in[11];
    float* out = (float*)d_out;

    // --- workspace overlay (~32.2 MB) ---
    char* S = (char*)d_ws;                          // 16 MB time-shared
    u16*   h_hi = (u16*)(S + (size_t)0);            // [0,4M)   phase 1
    u16*   h_lo = (u16*)(S + ((size_t)4 << 20));    // [4M,8M)
    float* qf   = (float*)(S + (size_t)0);          // [0,4M)   phase 2 (h dead)
    float* kf   = (float*)(S + ((size_t)4 << 20));  // [4M,8M)
    float* vf   = (float*)(S + ((size_t)8 << 20));  // [8M,12M)
    u16*   o_hi = (u16*)(S + ((size_t)12 << 20));   // [12M,14M)
    u16*   o_lo = (u16*)(S + ((size_t)14 << 20));   // [14M,16M)
    u16*   hid  = (u16*)(S + (size_t)0);            // [0,16M)  phase 4
    char* p = (char*)d_ws + ((size_t)16 << 20);
    u16*   c_hi   = (u16*)p;   p += (size_t)Tt * Ll * 2;      // 2 MB
    u16*   c_lo   = (u16*)p;   p += (size_t)Tt * Ll * 2;      // 2 MB
    u16*   t2h    = (u16*)p;   p += (size_t)Tt * Dd * 2;      // 4 MB
    float* x2f    = (float*)p; p += (size_t)Tt * Dd * 4;      // 8 MB
    float* gate_w = (float*)p; p += (size_t)Tt * 2 * 4;
    int*   counts = (int*)p;   p += 256;
    int*   l_tok  = (int*)p;   p += (size_t)Ee * Tt * 4;
    int*   l_gid  = (int*)p;   p += (size_t)Ee * Tt * 4;

    hipMemsetAsync(counts, 0, 256, stream);
    hipMemsetAsync(out, 0, (size_t)Tt * Dd * 4, stream);  // MoE accumulator

    rmsnorm1_k<<<Tt, 256, 0, stream>>>(x, g1, h_hi, h_lo);

    // c = h @ w_down  (split x split -> split-out)
    gemm_k<1, 1, 0, 0, 1, 0><<<dim3(Ll / 64, Tt / 64), 256, 0, stream>>>(
        h_hi, h_lo, w_down, nullptr, nullptr, Tt, Ll, Dd, Dd, Ll, Ll, 0, 0,
        nullptr, nullptr, nullptr, nullptr, nullptr, c_hi, c_lo, nullptr, nullptr);

    // q,k,v = c @ {wq,wk,wv}  merged over z (split x split, f32 out)
    gemm_k<1, 1, 0, 0, 0, 1><<<dim3(Ll / 64, Tt / 64, 3), 256, 0, stream>>>(
        c_hi, c_lo, wq, wk, wv, Tt, Ll, Ll, Ll, Ll, Ll, 0, (long)Tt * Ll,
        nullptr, nullptr, nullptr, nullptr, qf, nullptr, nullptr, nullptr, nullptr);

    rope_k<<<Tt, 256, 0, stream>>>(qf, kf);

    attn_k<<<dim3(Ss / 64, Bb * Hh), 256, 0, stream>>>(qf, kf, vf, o_hi, o_lo);

    // x2 = x + o @ w_up  (split x split, residual epilogue)
    gemm_k<1, 1, 0, 0, 2, 0><<<dim3(Dd / 64, Tt / 64), 256, 0, stream>>>(
        o_hi, o_lo, w_up, nullptr, nullptr, Tt, Dd, Ll, Ll, Dd, Dd, 0, 0,
        nullptr, nullptr, nullptr, nullptr, x2f, nullptr, nullptr, x, nullptr);

    rmsnorm2_router_k<<<Tt, 256, 0, stream>>>(x2f, g2, rw, t2h, gate_w,
                                              counts, l_tok, l_gid);

    // MoE GLU, merged over experts (z=8)
    gemm_k<0, 0, 1, 1, 3, 2><<<dim3(Ff / 64, Tt / 64, Ee), 256, 0, stream>>>(
        t2h, nullptr, w1, w3, nullptr, Tt, Ff, Dd, Dd, Ff, Ff,
        (long)Dd * Ff, 0, l_tok, l_gid, counts, nullptr,
        nullptr, nullptr, nullptr, nullptr, hid);

    // MoE down, merged over experts (z=8), atomic gated combine into out
    gemm_k<0, 0, 0, 1, 4, 2><<<dim3(Dd / 64, Tt / 64, Ee), 256, 0, stream>>>(
        hid, nullptr, w2, nullptr, nullptr, Tt, Dd, Ff, Ff, Dd, Dd,
        (long)Ff * Dd, 0, l_gid, l_gid, counts, gate_w,
        out, nullptr, nullptr, nullptr, nullptr);

    final_k<<<Tt, 256, 0, stream>>>(x2f, out);
}